// Round 6
// baseline (253.278 us; speedup 1.0000x reference)
//
#include <hip/hip_runtime.h>

// Problem constants: B=4, C=2, H=128, W=256 -> out (4,1,512,1024)
#define BB 4
#define CC 2
#define HH 128
#define WW 256
#define HO 512            // 4*H
#define WO4 256           // (4*W)/4 : one vec4 per coarse column j
#define PLANE (HO * WO4)  // vec4s per (b, ch) plane = 131072 (2 MB)

// Native clang vector type (__builtin_nontemporal_* rejects HIP's float4 class)
typedef float vf4 __attribute__((ext_vector_type(4)));

// CALIBRATION ROUND: best variant (R4: nt loads+stores, 256-thr direct),
// launched 3x back-to-back. The work is idempotent (out is pure overwrite),
// so correctness is unchanged; dur_us = fixed_harness + 3*T_kernel, and the
// delta vs R4's 204.5 us measures T_kernel = (dur_us - 204.5)/2 directly.
__global__ __launch_bounds__(256)
void spixel_upsample2d_kernel(const float* __restrict__ cv,
                              const vf4* __restrict__ sp,
                              vf4* __restrict__ out)
{
    const int j = threadIdx.x;        // coarse column = vec4 index
    const int y = blockIdx.x & 511;   // output row within batch
    const int b = blockIdx.x >> 9;    // batch
    const int i = y >> 2;             // coarse row

    const vf4* spb = sp + (size_t)(b * CC * 9) * PLANE + y * WO4 + j;
    vf4 acc = (vf4){0.f, 0.f, 0.f, 0.f};

    #pragma unroll
    for (int c = 0; c < CC; ++c) {
        // 9 patch weights for this channel: clamped load + select-0 for OOB.
        float w[9];
        #pragma unroll
        for (int ky = 0; ky < 3; ++ky) {
            const int ii  = i + ky - 1;
            const bool rowok = (ii >= 0) && (ii < HH);
            const int iic = rowok ? ii : 0;
            const float* cvrow = cv + ((b * CC + c) * HH + iic) * WW;
            #pragma unroll
            for (int kx = 0; kx < 3; ++kx) {
                const int jj  = j + kx - 1;
                const bool ok = rowok && (jj >= 0) && (jj < WW);
                const int jjc = (jj < 0) ? 0 : ((jj > WW - 1) ? WW - 1 : jj);
                const float v = cvrow[jjc];   // coalesced, L1/L2-hit
                w[ky * 3 + kx] = ok ? v : 0.0f;
            }
        }
        // 9 coalesced non-temporal vec4 loads at static 2 MB plane offsets.
        #pragma unroll
        for (int k = 0; k < 9; ++k) {
            const vf4 s = __builtin_nontemporal_load(spb + (size_t)(c * 9 + k) * PLANE);
            acc.x = fmaf(w[k], s.x, acc.x);
            acc.y = fmaf(w[k], s.y, acc.y);
            acc.z = fmaf(w[k], s.z, acc.z);
            acc.w = fmaf(w[k], s.w, acc.w);
        }
    }

    __builtin_nontemporal_store(acc, out + (size_t)(b * HO + y) * WO4 + j);
}

extern "C" void kernel_launch(void* const* d_in, const int* in_sizes, int n_in,
                              void* d_out, int out_size, void* d_ws, size_t ws_size,
                              hipStream_t stream) {
    const float* cv  = (const float*)d_in[0];   // (4,2,1,128,256)
    const vf4*   sp  = (const vf4*)d_in[1];     // (4,18,512,1024) as vec4
    vf4*         out = (vf4*)d_out;             // (4,1,512,1024)  as vec4

    const dim3 grid(BB * HO);   // 2048 blocks: one per (b, output row y)
    const dim3 block(256);
    // 3 identical launches: calibration of per-launch kernel time via dur_us.
    spixel_upsample2d_kernel<<<grid, block, 0, stream>>>(cv, sp, out);
    spixel_upsample2d_kernel<<<grid, block, 0, stream>>>(cv, sp, out);
    spixel_upsample2d_kernel<<<grid, block, 0, stream>>>(cv, sp, out);
}

// Round 7
// 202.660 us; speedup vs baseline: 1.2498x; 1.2498x over previous
//
#include <hip/hip_runtime.h>

// Problem constants: B=4, C=2, H=128, W=256 -> out (4,1,512,1024)
#define BB 4
#define CC 2
#define HH 128
#define WW 256
#define HO 512            // 4*H
#define WO4 256           // (4*W)/4 : one vec4 per coarse column j
#define PLANE (HO * WO4)  // vec4s per (b, ch) plane = 131072 (2 MB)

// Native clang vector type (__builtin_nontemporal_* rejects HIP's float4 class)
typedef float vf4 __attribute__((ext_vector_type(4)));

// FINAL (R4 variant, single launch). Measured at ~24.4 us device time via the
// R6 self-replication calibration: 160.4 MB compulsory HBM traffic at
// 6.57 TB/s = 97% of the 6.9 TB/s ceiling demonstrated by the harness's own
// 604 MB fill kernel on this machine. Memory-bound roofline; all remaining
// dur_us (~180 us) is fixed harness poison/restore traffic.
//
// Design: one thread per output vec4; 256-thr block = one (b, y) output row.
// cv (1 MB, 36x reuse) is read directly via clamped coalesced loads and
// stays L2-resident; sp (151 MB, zero reuse) streams through non-temporal
// vec4 loads at static 2 MB plane offsets; out (8.4 MB) uses nt stores.
__global__ __launch_bounds__(256)
void spixel_upsample2d_kernel(const float* __restrict__ cv,
                              const vf4* __restrict__ sp,
                              vf4* __restrict__ out)
{
    const int j = threadIdx.x;        // coarse column = vec4 index
    const int y = blockIdx.x & 511;   // output row within batch
    const int b = blockIdx.x >> 9;    // batch
    const int i = y >> 2;             // coarse row

    const vf4* spb = sp + (size_t)(b * CC * 9) * PLANE + y * WO4 + j;
    vf4 acc = (vf4){0.f, 0.f, 0.f, 0.f};

    #pragma unroll
    for (int c = 0; c < CC; ++c) {
        // 9 patch weights for this channel: clamped load + select-0 for OOB.
        float w[9];
        #pragma unroll
        for (int ky = 0; ky < 3; ++ky) {
            const int ii  = i + ky - 1;
            const bool rowok = (ii >= 0) && (ii < HH);
            const int iic = rowok ? ii : 0;
            const float* cvrow = cv + ((b * CC + c) * HH + iic) * WW;
            #pragma unroll
            for (int kx = 0; kx < 3; ++kx) {
                const int jj  = j + kx - 1;
                const bool ok = rowok && (jj >= 0) && (jj < WW);
                const int jjc = (jj < 0) ? 0 : ((jj > WW - 1) ? WW - 1 : jj);
                const float v = cvrow[jjc];   // coalesced, L1/L2-hit
                w[ky * 3 + kx] = ok ? v : 0.0f;
            }
        }
        // 9 coalesced non-temporal vec4 loads at static 2 MB plane offsets.
        #pragma unroll
        for (int k = 0; k < 9; ++k) {
            const vf4 s = __builtin_nontemporal_load(spb + (size_t)(c * 9 + k) * PLANE);
            acc.x = fmaf(w[k], s.x, acc.x);
            acc.y = fmaf(w[k], s.y, acc.y);
            acc.z = fmaf(w[k], s.z, acc.z);
            acc.w = fmaf(w[k], s.w, acc.w);
        }
    }

    __builtin_nontemporal_store(acc, out + (size_t)(b * HO + y) * WO4 + j);
}

extern "C" void kernel_launch(void* const* d_in, const int* in_sizes, int n_in,
                              void* d_out, int out_size, void* d_ws, size_t ws_size,
                              hipStream_t stream) {
    const float* cv  = (const float*)d_in[0];   // (4,2,1,128,256)
    const vf4*   sp  = (const vf4*)d_in[1];     // (4,18,512,1024) as vec4
    vf4*         out = (vf4*)d_out;             // (4,1,512,1024)  as vec4

    const dim3 grid(BB * HO);   // 2048 blocks: one per (b, output row y)
    const dim3 block(256);
    spixel_upsample2d_kernel<<<grid, block, 0, stream>>>(cv, sp, out);
}